// Round 12
// baseline (130.920 us; speedup 1.0000x reference)
//
#include <hip/hip_runtime.h>
#include <hip/hip_bf16.h>
#include <stdint.h>

typedef __attribute__((ext_vector_type(4))) float f32x4;
typedef __attribute__((ext_vector_type(8))) short short8;

#define NN 4096      // nodes
#define FIN 128
#define FHID 64
#define BATCH 32
#define NJ 2048      // BATCH * FHID

// ---------- helpers ----------
__device__ __forceinline__ unsigned short f2bf(float f) {
  unsigned u = __builtin_bit_cast(unsigned, f);
  u = (u + 0x7FFFu + ((u >> 16) & 1u)) >> 16;   // RNE
  return (unsigned short)u;
}
__device__ __forceinline__ float bf2f(unsigned short h) {
  unsigned u = ((unsigned)h) << 16;
  return __builtin_bit_cast(float, u);
}
__device__ __forceinline__ short8 pack8(f32x4 lo, f32x4 hi) {
  short8 w;
  #pragma unroll
  for (int j = 0; j < 4; ++j) {
    w[j]     = (short)f2bf(lo[j]);
    w[4 + j] = (short)f2bf(hi[j]);
  }
  return w;
}
__device__ __forceinline__ void gload_lds16(const void* g, void* l) {
  __builtin_amdgcn_global_load_lds(
      (const __attribute__((address_space(1))) unsigned int*)g,
      (__attribute__((address_space(3))) unsigned int*)l, 16, 0, 0);
}

// ---------- K1: St[b*64+h][m] = sum_f x[b][m][f] * W1[f][h]  (bf16 out) ----------
__global__ __launch_bounds__(256) void k_support(const float* __restrict__ x,
                                                 const float* __restrict__ W1,
                                                 unsigned short* __restrict__ St) {
  __shared__ unsigned short W1t[FHID * 136];              // [h][f], pad 136
  __shared__ __align__(16) unsigned short T[FHID * 128];  // [h][m_loc]
  const int tid = threadIdx.x;
  for (int i = tid; i < FIN * FHID; i += 256) {
    int f = i >> 6, h = i & 63;
    W1t[h * 136 + f] = f2bf(W1[i]);
  }
  __syncthreads();

  const int bb = blockIdx.x >> 5;
  const int m0 = (blockIdx.x & 31) * 128;
  const int lane = tid & 63, wv = tid >> 6;
  const int fr = lane & 15, fq = lane >> 4;

  short8 bfr[4][4];
  #pragma unroll
  for (int ni = 0; ni < 4; ++ni)
    #pragma unroll
    for (int ks = 0; ks < 4; ++ks)
      bfr[ni][ks] = *(const short8*)&W1t[(ni * 16 + fr) * 136 + ks * 32 + fq * 8];

  const float* xr0 = x + ((size_t)bb * NN + m0 + wv * 32 + fr) * FIN;
  const float* xr1 = xr0 + (size_t)16 * FIN;

  f32x4 z = {0.f, 0.f, 0.f, 0.f};
  f32x4 acc[2][4];
  #pragma unroll
  for (int mf = 0; mf < 2; ++mf)
    #pragma unroll
    for (int ni = 0; ni < 4; ++ni) acc[mf][ni] = z;

  #pragma unroll
  for (int ks = 0; ks < 4; ++ks) {
    #pragma unroll
    for (int mf = 0; mf < 2; ++mf) {
      const float* src = (mf ? xr1 : xr0) + ks * 32 + fq * 8;
      f32x4 lo = *(const f32x4*)src;
      f32x4 hi = *(const f32x4*)(src + 4);
      short8 a = pack8(lo, hi);
      #pragma unroll
      for (int ni = 0; ni < 4; ++ni)
        acc[mf][ni] = __builtin_amdgcn_mfma_f32_16x16x32_bf16(a, bfr[ni][ks], acc[mf][ni], 0, 0, 0);
    }
  }

  const int cr = (lane >> 4) * 4, cc = lane & 15;
  #pragma unroll
  for (int mf = 0; mf < 2; ++mf)
    #pragma unroll
    for (int ni = 0; ni < 4; ++ni) {
      ushort4 o;
      o.x = f2bf(acc[mf][ni][0]); o.y = f2bf(acc[mf][ni][1]);
      o.z = f2bf(acc[mf][ni][2]); o.w = f2bf(acc[mf][ni][3]);
      *(ushort4*)&T[(ni * 16 + cc) * 128 + wv * 32 + mf * 16 + cr] = o;
    }
  __syncthreads();
  for (int u = tid; u < FHID * 16; u += 256) {
    int row = u >> 4, ch = u & 15;
    *(short8*)(St + (size_t)(bb * FHID + row) * NN + m0 + ch * 8) =
        *(const short8*)&T[row * 128 + ch * 8];
  }
}

// ---------- K2: fused fp32-A GEMM + bias + relu + row-weighted aggregation ----------
// A = adj fp32 staged DIRECTLY via global_load_lds (no k_convert kernel);
// bf16 conversion at fragment-read (2x ds_read_b128 + pack8, hides under MFMA).
// R9-proven geometry/schedule: BM=256 x BN=128, BK=64, 8 waves 4M x 2N,
// per-wave 64x64, 4 single-barrier phases/K-tile, reg-dbuf bvA.
// LDS: A fp32 dbuf 128 KB + B bf16 dbuf 32 KB = 160 KB exactly (gfx950 max);
// epilogue adjw/red aliased into As after the K-loop.
// Staging: 10 gloads/tile {P1: A ch0-3, P2: B1, P3: A ch4-7 + B0};
// derived steady-state wait VMW(5) at P3, prologue VMW(10), tail 0.
// A-swizzle: byte ^= (row&15)<<4 (256B rows, 16 slots) via pre-swizzled
// global source; B-swizzle unchanged ((row&7)<<4). XCD-aware block decode.
#define VMW(N)  asm volatile("s_waitcnt vmcnt(" #N ")" ::: "memory")
#define LGKM0   asm volatile("s_waitcnt lgkmcnt(0)" ::: "memory")
#define BAR     __builtin_amdgcn_s_barrier()

__global__ __launch_bounds__(512, 1) void k_gemm(const float* __restrict__ Af,
                                                 const unsigned short* __restrict__ Bt,
                                                 const float* __restrict__ b1,
                                                 const int* __restrict__ q_ids,
                                                 float* __restrict__ partial) {
  __shared__ __align__(16) float Asf[2 * 16384];          // A fp32: 256x64 dbuf, 128 KB
  __shared__ __align__(16) unsigned short Bs[2 * 8192];   // B bf16: 128x64 dbuf, 32 KB

  const int tid  = threadIdx.x;
  const int lane = tid & 63;
  const int wv   = tid >> 6;
  const int wm   = wv >> 1;          // 0..3 (M)
  const int wn   = wv & 1;           // 0..1 (N)
  // XCD-aware decode: XCD c = bid%8 gets x-panels {2c, 2c+1} (A L2 locality)
  const int bid  = blockIdx.x;
  const int xc   = bid & 7;
  const int kk   = bid >> 3;         // 0..31
  const int bx   = xc * 2 + (kk >> 4);
  const int by   = kk & 15;
  const int bm   = bx * 256;
  const int bn   = by * 128;
  const int fr   = lane & 15;
  const int fq   = lane >> 4;

  // A fragment LDS offsets (float units): two b128 halves per (h,m2,ks)
  int offAF[2][2][2][2];
  #pragma unroll
  for (int h = 0; h < 2; ++h)
    #pragma unroll
    for (int m2 = 0; m2 < 2; ++m2) {
      int row = wm * 32 + h * 128 + m2 * 16 + fr;
      #pragma unroll
      for (int ks = 0; ks < 2; ++ks)
        #pragma unroll
        for (int hf = 0; hf < 2; ++hf) {
          int byte = (ks * 128 + fq * 32 + hf * 16) ^ ((row & 15) << 4);
          offAF[h][m2][ks][hf] = row * 64 + (byte >> 2);
        }
    }
  // B fragment LDS offsets (ushort units), unchanged from R9
  int offB[4][2];
  #pragma unroll
  for (int ni = 0; ni < 4; ++ni) {
    int row = wn * 32 + (ni & 1) * 16 + (ni >> 1) * 64 + fr;
    #pragma unroll
    for (int ks = 0; ks < 2; ++ks)
      offB[ni][ks] = row * 64 + ((((ks << 6) + (fq << 4)) ^ ((row & 7) << 4)) >> 1);
  }

  // A staging: 8 chunks x 32 rows x 256 B; 16 threads/row
  const int srowA = tid >> 4;                                  // 0..31
  const int scolA = ((((tid & 15) << 4) ^ ((srowA & 15) << 4)) >> 2);  // float idx
  const float* gAF[8];
  #pragma unroll
  for (int c = 0; c < 8; ++c)
    gAF[c] = Af + (size_t)(bm + 32 * c + srowA) * NN + scolA;
  const int ldA = tid * 4;   // float offset of this thread's 16B slot in a chunk
  // B staging: 2 chunks x 64 rows x 128 B; 8 threads/row (R9-exact)
  const int srowB = tid >> 3;                                  // 0..63
  const int scolB = ((((tid & 7) << 4) ^ ((srowB & 7) << 4)) >> 1);    // ushort idx
  const unsigned short* gB0 = Bt + (size_t)(bn +  0 + srowB) * NN + scolB;
  const unsigned short* gB1 = Bt + (size_t)(bn + 64 + srowB) * NN + scolB;
  const int ldB = tid * 8;   // ushort offset of this thread's 16B slot

  f32x4 z = {0.f, 0.f, 0.f, 0.f};
  f32x4 acc[4][4];
  #pragma unroll
  for (int i = 0; i < 4; ++i)
    #pragma unroll
    for (int j = 0; j < 4; ++j) acc[i][j] = z;

  short8 av0[2][2], av1[2][2], bvB[2][2], bvA0[2][2], bvA1[2][2];

#define RD_AVA(Ac)                                                             \
    _Pragma("unroll") for (int m2 = 0; m2 < 2; ++m2)                           \
    _Pragma("unroll") for (int ks = 0; ks < 2; ++ks) {                         \
      f32x4 lo = *(const f32x4*)((Ac) + offAF[0][m2][ks][0]);                  \
      f32x4 hi = *(const f32x4*)((Ac) + offAF[0][m2][ks][1]);                  \
      av0[m2][ks] = pack8(lo, hi);                                             \
    }
#define RD_AVB(Ac)                                                             \
    _Pragma("unroll") for (int m2 = 0; m2 < 2; ++m2)                           \
    _Pragma("unroll") for (int ks = 0; ks < 2; ++ks) {                         \
      f32x4 lo = *(const f32x4*)((Ac) + offAF[1][m2][ks][0]);                  \
      f32x4 hi = *(const f32x4*)((Ac) + offAF[1][m2][ks][1]);                  \
      av1[m2][ks] = pack8(lo, hi);                                             \
    }
#define RD_BV(DST, Bb, P)                                                      \
    _Pragma("unroll") for (int n2 = 0; n2 < 2; ++n2)                           \
    _Pragma("unroll") for (int ks = 0; ks < 2; ++ks)                           \
      DST[n2][ks] = *(const short8*)((Bb) + offB[2 * (P) + n2][ks]);
#define MFMA8(MP, AV, BV, NP)                                                  \
    __builtin_amdgcn_s_setprio(1);                                             \
    _Pragma("unroll") for (int m2 = 0; m2 < 2; ++m2)                           \
    _Pragma("unroll") for (int n2 = 0; n2 < 2; ++n2)                           \
    _Pragma("unroll") for (int ks = 0; ks < 2; ++ks)                           \
      acc[2 * (MP) + m2][2 * (NP) + n2] = __builtin_amdgcn_mfma_f32_16x16x32_bf16( \
          AV[m2][ks], BV[n2][ks], acc[2 * (MP) + m2][2 * (NP) + n2], 0, 0, 0); \
    __builtin_amdgcn_s_setprio(0);
#define SG_AF(C, KO, BUF) gload_lds16(gAF[C] + (KO), Asf + (BUF) * 16384 + (C) * 2048 + ldA);
#define SG_B0(KO, BUF)    gload_lds16(gB0 + (KO), Bs + (BUF) * 8192 + 0 * 4096 + ldB);
#define SG_B1(KO, BUF)    gload_lds16(gB1 + (KO), Bs + (BUF) * 8192 + 1 * 4096 + ldB);

// One K-tile, 4 single-barrier phases (R9 guards; A fp32):
// A-h0 = chunks 0-3 (rows [0,128), read P0); A-h1 = chunks 4-7 (read P2);
// B np1 read P1; B np0 read prev-P3 (bvA reg-dbuf).
// Stages (t+2 -> CUR): P1: A0-3 ; P2: B1 ; P3: A4-7 + B0. Wait: VMW(5).
#define TILE(CUR, BVA_C, BVA_N, KQ, DOS, VMWOP) {                              \
    const float* Ac = Asf + (CUR) * 16384;                                     \
    const unsigned short* Bc = Bs + (CUR) * 8192;                              \
    const unsigned short* Bn = Bs + (1 - (CUR)) * 8192;                        \
    /* P0: Q(0,0) */                                                           \
    RD_AVA(Ac)                                                                 \
    BAR; LGKM0;                                                                \
    MFMA8(0, av0, BVA_C, 0)                                                    \
    /* P1: Q(0,1); stage A ch0-3 (t+2) */                                      \
    RD_BV(bvB, Bc, 1)                                                          \
    if (DOS) { SG_AF(0, KQ, CUR) SG_AF(1, KQ, CUR)                             \
               SG_AF(2, KQ, CUR) SG_AF(3, KQ, CUR) }                           \
    BAR; LGKM0;                                                                \
    MFMA8(0, av0, bvB, 1)                                                      \
    /* P2: Q(1,1); stage B1 (t+2) */                                           \
    RD_AVB(Ac)                                                                 \
    if (DOS) { SG_B1(KQ, CUR) }                                                \
    BAR; LGKM0;                                                                \
    MFMA8(1, av1, bvB, 1)                                                      \
    /* P3: Q(1,0); counted vmcnt; stage A ch4-7 + B0 (t+2); read bvA(t+1) */   \
    VMWOP;                                                                     \
    if (DOS) { SG_AF(4, KQ, CUR) SG_AF(5, KQ, CUR)                             \
               SG_AF(6, KQ, CUR) SG_AF(7, KQ, CUR)                             \
               SG_B0(KQ, CUR) }                                                \
    BAR;                                                                       \
    RD_BV(BVA_N, Bn, 0)                                                        \
    MFMA8(1, av1, BVA_C, 0)                                                    \
  }

  // ---- prologue: stage tile0 -> buf0, tile1 -> buf1 (10 gloads each) ----
  #pragma unroll
  for (int c = 0; c < 8; ++c) { SG_AF(c, 0, 0) }
  SG_B0(0, 0) SG_B1(0, 0)
  #pragma unroll
  for (int c = 0; c < 8; ++c) { SG_AF(c, 64, 1) }
  SG_B0(64, 1) SG_B1(64, 1)
  VMW(10);                // tile0's 10 loads landed; tile1 in flight
  BAR;
  RD_BV(bvA0, Bs, 0)      // prime bvA for tile 0 (drained at tile0 P0 LGKM0)

  // ---- main loop: 31 macro-iters = tiles 0..61 (stage t+2) ----
  int kq = 128;
  #pragma unroll 1
  for (int g = 0; g < 31; ++g) {
    TILE(0, bvA0, bvA1, kq,      1, VMW(5))
    TILE(1, bvA1, bvA0, kq + 64, 1, VMW(5))
    kq += 128;
  }
  // ---- tile 62 (buf0): no staging; drain for tile 63 ----
  TILE(0, bvA0, bvA1, 0, 0, VMW(0))
  // ---- tile 63 (buf1): last, no bvA-next / no vmcnt ----
  {
    const float* Ac = Asf + 16384;
    const unsigned short* Bc = Bs + 8192;
    RD_AVA(Ac)
    BAR; LGKM0;
    MFMA8(0, av0, bvA1, 0)
    RD_BV(bvB, Bc, 1)
    BAR; LGKM0;
    MFMA8(0, av0, bvB, 1)
    RD_AVB(Ac)
    BAR; LGKM0;
    MFMA8(1, av1, bvB, 1)
    MFMA8(1, av1, bvA1, 0)
  }
#undef RD_AVA
#undef RD_AVB
#undef RD_BV
#undef MFMA8
#undef SG_AF
#undef SG_B0
#undef SG_B1
#undef TILE

  // ---- fused epilogue (LDS aliased into Asf): bias+relu+weight+reduce ----
  float* adjwF = (float*)Asf;          // [2][256]
  float* redF  = (float*)Asf + 512;    // [8][64]
  __syncthreads();                     // all waves' LDS reads complete
  const int b0 = bn >> 6;
  {
    int bsel = tid >> 8;               // 0 or 1
    int rloc = tid & 255;
    adjwF[bsel * 256 + rloc] = Af[(size_t)q_ids[b0 + bsel] * NN + bm + rloc];
  }
  __syncthreads();

  const int cr = (lane >> 4) * 4;
  const int cc = lane & 15;
  float ps[4];
  #pragma unroll
  for (int ni = 0; ni < 4; ++ni) {
    int colh = wn * 32 + (ni & 1) * 16 + cc;   // h index (col & 63)
    float bias = b1[colh];
    float s = 0.f;
    #pragma unroll
    for (int mi = 0; mi < 4; ++mi) {
      int rowl = wm * 32 + (mi & 1) * 16 + (mi >> 1) * 128 + cr;
      #pragma unroll
      for (int r = 0; r < 4; ++r) {
        float v = acc[mi][ni][r] + bias;
        v = v > 0.f ? v : 0.f;
        s += adjwF[(ni >> 1) * 256 + rowl + r] * v;
      }
    }
    ps[ni] = s;
  }
  // reduce across fq groups (lanes differing in bits 4,5)
  #pragma unroll
  for (int ni = 0; ni < 4; ++ni) {
    ps[ni] += __shfl_xor(ps[ni], 16, 64);
    ps[ni] += __shfl_xor(ps[ni], 32, 64);
  }
  if (lane < 16) {
    #pragma unroll
    for (int ni = 0; ni < 4; ++ni)
      redF[(wm * 2 + wn) * 64 + ni * 16 + cc] = ps[ni];
  }
  __syncthreads();
  if (tid < 128) {
    int wn2 = (tid >> 5) & 1;
    int ni2 = ((tid >> 6) << 1) | ((tid >> 4) & 1);
    int sidx = ni2 * 16 + (tid & 15);
    float s = redF[(0 + wn2) * 64 + sidx] + redF[(2 + wn2) * 64 + sidx]
            + redF[(4 + wn2) * 64 + sidx] + redF[(6 + wn2) * 64 + sidx];
    partial[(size_t)bx * NJ + bn + tid] = s;
  }
}

// ---------- K4: out[b][l] = sum_h (sum_rb partial[rb][b*64+h]) * W2[h][l] + b2[l] ----------
__global__ __launch_bounds__(1024) void k_out(const float* __restrict__ partial,
                                              const float* __restrict__ W2,
                                              const float* __restrict__ b2,
                                              float* __restrict__ out) {
  __shared__ float aggs[BATCH * FHID];   // 2048
  int t = threadIdx.x;
  for (int idx = t; idx < BATCH * FHID; idx += 1024) {
    float s = 0.f;
    #pragma unroll
    for (int c = 0; c < 16; ++c) s += partial[c * NJ + idx];
    aggs[idx] = s;
  }
  __syncthreads();
  int b = t >> 5, l = t & 31;
  float o = b2[l];
  #pragma unroll
  for (int h = 0; h < FHID; ++h) o += aggs[b * FHID + h] * W2[h * 32 + l];
  out[b * 32 + l] = o;
}

extern "C" void kernel_launch(void* const* d_in, const int* in_sizes, int n_in,
                              void* d_out, int out_size, void* d_ws, size_t ws_size,
                              hipStream_t stream) {
  const float* x   = (const float*)d_in[0];
  const int*   q   = (const int*)d_in[1];
  const float* adj = (const float*)d_in[2];
  const float* W1  = (const float*)d_in[3];
  const float* b1  = (const float*)d_in[4];
  const float* W2  = (const float*)d_in[5];
  const float* b2  = (const float*)d_in[6];
  float* out = (float*)d_out;

  char* ws = (char*)d_ws;
  unsigned short* St     = (unsigned short*)ws;                               // 16 MB
  float*          partial= (float*)(ws + (size_t)16 * 1024 * 1024);           // 128 KB

  // K1: support^T via MFMA
  k_support<<<1024, 256, 0, stream>>>(x, W1, St);
  // K2: fused fp32-A GEMM + bias/relu + aggregation (no k_convert, no H)
  k_gemm<<<256, 512, 0, stream>>>(adj, St, b1, q, partial);
  // K3: reduce partials + final tiny GEMM
  k_out<<<1, 1024, 0, stream>>>(partial, W2, b2, out);
}

// Round 13
// 101.309 us; speedup vs baseline: 1.2923x; 1.2923x over previous
//
#include <hip/hip_runtime.h>
#include <hip/hip_bf16.h>
#include <stdint.h>

typedef __attribute__((ext_vector_type(4))) float f32x4;
typedef __attribute__((ext_vector_type(8))) short short8;

#define NN 4096      // nodes
#define FIN 128
#define FHID 64
#define BATCH 32
#define NJ 2048      // BATCH * FHID

// ---------- helpers ----------
__device__ __forceinline__ unsigned short f2bf(float f) {
  unsigned u = __builtin_bit_cast(unsigned, f);
  u = (u + 0x7FFFu + ((u >> 16) & 1u)) >> 16;   // RNE
  return (unsigned short)u;
}
__device__ __forceinline__ float bf2f(unsigned short h) {
  unsigned u = ((unsigned)h) << 16;
  return __builtin_bit_cast(float, u);
}
__device__ __forceinline__ void gload_lds16(const void* g, void* l) {
  __builtin_amdgcn_global_load_lds(
      (const __attribute__((address_space(1))) unsigned int*)g,
      (__attribute__((address_space(3))) unsigned int*)l, 16, 0, 0);
}

// ---------- K0: adj fp32 -> bf16 ----------
__global__ __launch_bounds__(256) void k_convert(const float* __restrict__ adj,
                                                 unsigned short* __restrict__ adjb) {
  long i = (long)blockIdx.x * 256 + threadIdx.x;
  const f32x4* in = (const f32x4*)adj;
  f32x4 v = in[i];
  ushort4 o;
  o.x = f2bf(v.x); o.y = f2bf(v.y); o.z = f2bf(v.z); o.w = f2bf(v.w);
  *(ushort4*)(adjb + i * 4) = o;
}

// ---------- K1: St[b*64+h][m] = sum_f x[b][m][f] * W1[f][h]  (bf16 out) ----------
__global__ __launch_bounds__(256) void k_support(const float* __restrict__ x,
                                                 const float* __restrict__ W1,
                                                 unsigned short* __restrict__ St) {
  __shared__ unsigned short W1t[FHID * 136];              // [h][f], pad 136
  __shared__ __align__(16) unsigned short T[FHID * 128];  // [h][m_loc]
  const int tid = threadIdx.x;
  for (int i = tid; i < FIN * FHID; i += 256) {
    int f = i >> 6, h = i & 63;
    W1t[h * 136 + f] = f2bf(W1[i]);
  }
  __syncthreads();

  const int bb = blockIdx.x >> 5;
  const int m0 = (blockIdx.x & 31) * 128;
  const int lane = tid & 63, wv = tid >> 6;
  const int fr = lane & 15, fq = lane >> 4;

  short8 bfr[4][4];
  #pragma unroll
  for (int ni = 0; ni < 4; ++ni)
    #pragma unroll
    for (int ks = 0; ks < 4; ++ks)
      bfr[ni][ks] = *(const short8*)&W1t[(ni * 16 + fr) * 136 + ks * 32 + fq * 8];

  const float* xr0 = x + ((size_t)bb * NN + m0 + wv * 32 + fr) * FIN;
  const float* xr1 = xr0 + (size_t)16 * FIN;

  f32x4 z = {0.f, 0.f, 0.f, 0.f};
  f32x4 acc[2][4];
  #pragma unroll
  for (int mf = 0; mf < 2; ++mf)
    #pragma unroll
    for (int ni = 0; ni < 4; ++ni) acc[mf][ni] = z;

  #pragma unroll
  for (int ks = 0; ks < 4; ++ks) {
    #pragma unroll
    for (int mf = 0; mf < 2; ++mf) {
      const float* src = (mf ? xr1 : xr0) + ks * 32 + fq * 8;
      f32x4 lo = *(const f32x4*)src;
      f32x4 hi = *(const f32x4*)(src + 4);
      short8 a;
      #pragma unroll
      for (int j = 0; j < 4; ++j) { a[j] = (short)f2bf(lo[j]); a[4 + j] = (short)f2bf(hi[j]); }
      #pragma unroll
      for (int ni = 0; ni < 4; ++ni)
        acc[mf][ni] = __builtin_amdgcn_mfma_f32_16x16x32_bf16(a, bfr[ni][ks], acc[mf][ni], 0, 0, 0);
    }
  }

  const int cr = (lane >> 4) * 4, cc = lane & 15;
  #pragma unroll
  for (int mf = 0; mf < 2; ++mf)
    #pragma unroll
    for (int ni = 0; ni < 4; ++ni) {
      ushort4 o;
      o.x = f2bf(acc[mf][ni][0]); o.y = f2bf(acc[mf][ni][1]);
      o.z = f2bf(acc[mf][ni][2]); o.w = f2bf(acc[mf][ni][3]);
      *(ushort4*)&T[(ni * 16 + cc) * 128 + wv * 32 + mf * 16 + cr] = o;
    }
  __syncthreads();
  for (int u = tid; u < FHID * 16; u += 256) {
    int row = u >> 4, ch = u & 15;
    *(short8*)(St + (size_t)(bb * FHID + row) * NN + m0 + ch * 8) =
        *(const short8*)&T[row * 128 + ch * 8];
  }
}

// ---------- K2: fused GEMM + bias + relu + row-weighted aggregation ----------
// K-loop: R5-proven schedule (benched 65.4 us here): BM=256 x BN=128, BK=64,
// 8 waves 4M x 2N, per-wave 64x64, dbuf LDS 96 KB, 4 single-barrier
// phases/K-tile, reg-dbuf bvA, one vmcnt(3)/tile, XOR-swizzle via
// pre-swizzled global source.
// Epilogue: weight relu(acc+bias) by adj[q_b][row], reduce over the block's
// 256 rows -> partial[rowblock][col] (fp32). No H buffer (saves 32 MB traffic).
#define VMW(N)  asm volatile("s_waitcnt vmcnt(" #N ")" ::: "memory")
#define LGKM0   asm volatile("s_waitcnt lgkmcnt(0)" ::: "memory")
#define BAR     __builtin_amdgcn_s_barrier()

__global__ __launch_bounds__(512, 1) void k_gemm(const unsigned short* __restrict__ A,
                                                 const unsigned short* __restrict__ Bt,
                                                 const float* __restrict__ b1,
                                                 const float* __restrict__ adj,
                                                 const int* __restrict__ q_ids,
                                                 float* __restrict__ partial) {
  __shared__ __align__(16) unsigned short As[2 * 16384];  // A: 256x64 dbuf, 64 KB
  __shared__ __align__(16) unsigned short Bs[2 * 8192];   // B: 128x64 dbuf, 32 KB
  __shared__ float adjw[2][256];                          // 2 KB (epilogue)
  __shared__ float red[8][64];                            // 2 KB (epilogue)

  const int tid  = threadIdx.x;
  const int lane = tid & 63;
  const int wv   = tid >> 6;
  const int wm   = wv >> 1;          // 0..3 (M)
  const int wn   = wv & 1;           // 0..1 (N)
  const int bm   = blockIdx.x * 256;
  const int bn   = blockIdx.y * 128;
  const int fr   = lane & 15;
  const int fq   = lane >> 4;

  // fragment LDS ushort offsets (buffer-relative)
  int offA[2][2][2], offB[4][2];
  #pragma unroll
  for (int h = 0; h < 2; ++h)
    #pragma unroll
    for (int m2 = 0; m2 < 2; ++m2) {
      int row = wm * 32 + h * 128 + m2 * 16 + fr;
      #pragma unroll
      for (int ks = 0; ks < 2; ++ks)
        offA[h][m2][ks] = row * 64 + ((((ks << 6) + (fq << 4)) ^ ((row & 7) << 4)) >> 1);
    }
  #pragma unroll
  for (int ni = 0; ni < 4; ++ni) {
    int row = wn * 32 + (ni & 1) * 16 + (ni >> 1) * 64 + fr;
    #pragma unroll
    for (int ks = 0; ks < 2; ++ks)
      offB[ni][ks] = row * 64 + ((((ks << 6) + (fq << 4)) ^ ((row & 7) << 4)) >> 1);
  }

  // staging addresses (pre-swizzled global source, linear LDS dest)
  const int srow = tid >> 3;
  const int scol = ((((tid & 7) << 4) ^ ((srow & 7) << 4)) >> 1);
  const unsigned short* gA00 = A + (size_t)(bm +   0 + srow) * NN + scol;
  const unsigned short* gA01 = A + (size_t)(bm +  64 + srow) * NN + scol;
  const unsigned short* gA10 = A + (size_t)(bm + 128 + srow) * NN + scol;
  const unsigned short* gA11 = A + (size_t)(bm + 192 + srow) * NN + scol;
  const unsigned short* gB0  = Bt + (size_t)(bn +  0 + srow) * NN + scol;
  const unsigned short* gB1  = Bt + (size_t)(bn + 64 + srow) * NN + scol;
  const int ld = tid * 8;

  f32x4 z = {0.f, 0.f, 0.f, 0.f};
  f32x4 acc[4][4];
  #pragma unroll
  for (int i = 0; i < 4; ++i)
    #pragma unroll
    for (int j = 0; j < 4; ++j) acc[i][j] = z;

  short8 av0[2][2], av1[2][2], bvB[2][2], bvA0[2][2], bvA1[2][2];

#define RD_AVA(Ac)                                                             \
    _Pragma("unroll") for (int m2 = 0; m2 < 2; ++m2)                           \
    _Pragma("unroll") for (int ks = 0; ks < 2; ++ks)                           \
      av0[m2][ks] = *(const short8*)((Ac) + offA[0][m2][ks]);
#define RD_AVB(Ac)                                                             \
    _Pragma("unroll") for (int m2 = 0; m2 < 2; ++m2)                           \
    _Pragma("unroll") for (int ks = 0; ks < 2; ++ks)                           \
      av1[m2][ks] = *(const short8*)((Ac) + offA[1][m2][ks]);
#define RD_BV(DST, Bb, P)                                                      \
    _Pragma("unroll") for (int n2 = 0; n2 < 2; ++n2)                           \
    _Pragma("unroll") for (int ks = 0; ks < 2; ++ks)                           \
      DST[n2][ks] = *(const short8*)((Bb) + offB[2 * (P) + n2][ks]);
#define MFMA8(MP, AV, BV, NP)                                                  \
    __builtin_amdgcn_s_setprio(1);                                             \
    _Pragma("unroll") for (int m2 = 0; m2 < 2; ++m2)                           \
    _Pragma("unroll") for (int n2 = 0; n2 < 2; ++n2)                           \
    _Pragma("unroll") for (int ks = 0; ks < 2; ++ks)                           \
      acc[2 * (MP) + m2][2 * (NP) + n2] = __builtin_amdgcn_mfma_f32_16x16x32_bf16( \
          AV[m2][ks], BV[n2][ks], acc[2 * (MP) + m2][2 * (NP) + n2], 0, 0, 0); \
    __builtin_amdgcn_s_setprio(0);

#define TILE(CUR, BVA_C, BVA_N, KQ, DOS, VMWOP) {                              \
    const unsigned short* Ac = As + (CUR) * 16384;                             \
    const unsigned short* Bc = Bs + (CUR) * 8192;                              \
    const unsigned short* Bn = Bs + (1 - (CUR)) * 8192;                        \
    /* P0: Q(0,0) */                                                           \
    RD_AVA(Ac)                                                                 \
    BAR; LGKM0;                                                                \
    MFMA8(0, av0, BVA_C, 0)                                                    \
    /* P1: Q(0,1); stage A-h0(t+2) */                                          \
    RD_BV(bvB, Bc, 1)                                                          \
    if (DOS) {                                                                 \
      gload_lds16(gA00 + (KQ), As + (CUR) * 16384 + 0 * 4096 + ld);            \
      gload_lds16(gA01 + (KQ), As + (CUR) * 16384 + 1 * 4096 + ld);            \
    }                                                                          \
    BAR; LGKM0;                                                                \
    MFMA8(0, av0, bvB, 1)                                                      \
    /* P2: Q(1,1); stage B-h1(t+2) */                                          \
    RD_AVB(Ac)                                                                 \
    if (DOS) {                                                                 \
      gload_lds16(gB1 + (KQ), Bs + (CUR) * 8192 + 1 * 4096 + ld);              \
    }                                                                          \
    BAR; LGKM0;                                                                \
    MFMA8(1, av1, bvB, 1)                                                      \
    /* P3: Q(1,0); vmcnt; stage A-h1,B-h0(t+2); read bvA(t+1) post-barrier */  \
    VMWOP;                                                                     \
    if (DOS) {                                                                 \
      gload_lds16(gA10 + (KQ), As + (CUR) * 16384 + 2 * 4096 + ld);            \
      gload_lds16(gA11 + (KQ), As + (CUR) * 16384 + 3 * 4096 + ld);            \
      gload_lds16(gB0  + (KQ), Bs + (CUR) * 8192 + 0 * 4096 + ld);             \
    }                                                                          \
    BAR;                                                                       \
    RD_BV(BVA_N, Bn, 0)                                                        \
    MFMA8(1, av1, BVA_C, 0)                                                    \
  }

  // ---- prologue: stage tile0 -> buf0, tile1 -> buf1 ----
  gload_lds16(gB0,       Bs + 0 * 4096 + ld);
  gload_lds16(gB1,       Bs + 1 * 4096 + ld);
  gload_lds16(gA00,      As + 0 * 4096 + ld);
  gload_lds16(gA01,      As + 1 * 4096 + ld);
  gload_lds16(gA10,      As + 2 * 4096 + ld);
  gload_lds16(gA11,      As + 3 * 4096 + ld);
  gload_lds16(gB0  + 64, Bs + 8192 + 0 * 4096 + ld);
  gload_lds16(gB1  + 64, Bs + 8192 + 1 * 4096 + ld);
  gload_lds16(gA00 + 64, As + 16384 + 0 * 4096 + ld);
  gload_lds16(gA01 + 64, As + 16384 + 1 * 4096 + ld);
  gload_lds16(gA10 + 64, As + 16384 + 2 * 4096 + ld);
  gload_lds16(gA11 + 64, As + 16384 + 3 * 4096 + ld);
  VMW(6);                 // own tile-0 loads drained
  BAR;                    // => all waves' tile-0 loads visible
  RD_BV(bvA0, Bs, 0)      // prime bvA for tile 0 (waited at tile0 P0 LGKM0)

  // ---- main loop: 31 macro-iters = tiles 0..61 ----
  int kq = 128;           // k-elem offset of tile t+2
  #pragma unroll 1
  for (int g = 0; g < 31; ++g) {
    TILE(0, bvA0, bvA1, kq,      1, VMW(3))
    TILE(1, bvA1, bvA0, kq + 64, 1, VMW(3))
    kq += 128;
  }
  // ---- tile 62 (buf0): no staging; drain for tile 63 ----
  TILE(0, bvA0, bvA1, 0, 0, VMW(0))
  // ---- tile 63 (buf1): last, no bvA-next / no vmcnt ----
  {
    const unsigned short* Ac = As + 16384;
    const unsigned short* Bc = Bs + 8192;
    RD_AVA(Ac)
    BAR; LGKM0;
    MFMA8(0, av0, bvA1, 0)
    RD_BV(bvB, Bc, 1)
    BAR; LGKM0;
    MFMA8(0, av0, bvB, 1)
    RD_AVB(Ac)
    BAR; LGKM0;
    MFMA8(1, av1, bvB, 1)
    MFMA8(1, av1, bvA1, 0)
  }
#undef RD_AVA
#undef RD_AVB
#undef RD_BV
#undef MFMA8
#undef TILE

  // ---- fused epilogue: bias + relu + weight by adj[q_b][row] + reduce ----
  // Load the two adj rows needed for this col-block's batches (b0, b0+1).
  const int b0 = bn >> 6;
  {
    int bsel = tid >> 8;           // 0 or 1
    int rloc = tid & 255;
    adjw[bsel][rloc] = adj[(size_t)q_ids[b0 + bsel] * NN + bm + rloc];
  }
  __syncthreads();

  const int cr = (lane >> 4) * 4;
  const int cc = lane & 15;
  float ps[4];
  #pragma unroll
  for (int ni = 0; ni < 4; ++ni) {
    int colh = wn * 32 + (ni & 1) * 16 + cc;   // h index (col & 63)
    float bias = b1[colh];
    float s = 0.f;
    #pragma unroll
    for (int mi = 0; mi < 4; ++mi) {
      int rowl = wm * 32 + (mi & 1) * 16 + (mi >> 1) * 128 + cr;
      #pragma unroll
      for (int r = 0; r < 4; ++r) {
        float v = acc[mi][ni][r] + bias;
        v = v > 0.f ? v : 0.f;
        s += adjw[ni >> 1][rowl + r] * v;
      }
    }
    ps[ni] = s;
  }
  // reduce across fq groups (lanes differing in bits 4,5)
  #pragma unroll
  for (int ni = 0; ni < 4; ++ni) {
    ps[ni] += __shfl_xor(ps[ni], 16, 64);
    ps[ni] += __shfl_xor(ps[ni], 32, 64);
  }
  if (lane < 16) {
    #pragma unroll
    for (int ni = 0; ni < 4; ++ni)
      red[wm * 2 + wn][ni * 16 + cc] = ps[ni];
  }
  __syncthreads();
  if (tid < 128) {
    int colLocal = tid;
    int wn2 = (colLocal >> 5) & 1;
    int ni2 = ((colLocal >> 6) << 1) | ((colLocal >> 4) & 1);
    int cc2 = colLocal & 15;
    float s = red[0 + wn2][ni2 * 16 + cc2] + red[2 + wn2][ni2 * 16 + cc2]
            + red[4 + wn2][ni2 * 16 + cc2] + red[6 + wn2][ni2 * 16 + cc2];
    partial[(size_t)blockIdx.x * NJ + bn + colLocal] = s;
  }
}

// ---------- K4: out[b][l] = sum_h (sum_rb partial[rb][b*64+h]) * W2[h][l] + b2[l] ----------
__global__ __launch_bounds__(1024) void k_out(const float* __restrict__ partial,
                                              const float* __restrict__ W2,
                                              const float* __restrict__ b2,
                                              float* __restrict__ out) {
  __shared__ float aggs[BATCH * FHID];   // 2048
  int t = threadIdx.x;
  for (int idx = t; idx < BATCH * FHID; idx += 1024) {
    float s = 0.f;
    #pragma unroll
    for (int c = 0; c < 16; ++c) s += partial[c * NJ + idx];
    aggs[idx] = s;
  }
  __syncthreads();
  int b = t >> 5, l = t & 31;
  float o = b2[l];
  #pragma unroll
  for (int h = 0; h < FHID; ++h) o += aggs[b * FHID + h] * W2[h * 32 + l];
  out[b * 32 + l] = o;
}

extern "C" void kernel_launch(void* const* d_in, const int* in_sizes, int n_in,
                              void* d_out, int out_size, void* d_ws, size_t ws_size,
                              hipStream_t stream) {
  const float* x   = (const float*)d_in[0];
  const int*   q   = (const int*)d_in[1];
  const float* adj = (const float*)d_in[2];
  const float* W1  = (const float*)d_in[3];
  const float* b1  = (const float*)d_in[4];
  const float* W2  = (const float*)d_in[5];
  const float* b2  = (const float*)d_in[6];
  float* out = (float*)d_out;

  char* ws = (char*)d_ws;
  unsigned short* adjb   = (unsigned short*)ws;                              // 32 MB
  unsigned short* St     = (unsigned short*)(ws + (size_t)32 * 1024 * 1024); // 16 MB
  float*          partial= (float*)(ws + (size_t)48 * 1024 * 1024);          // 128 KB

  // K0: adj -> bf16
  k_convert<<<(NN * NN / 4) / 256, 256, 0, stream>>>(adj, adjb);
  // K1: support^T via MFMA
  k_support<<<1024, 256, 0, stream>>>(x, W1, St);
  // K2: fused GEMM + bias/relu + row-weighted aggregation (no H buffer)
  dim3 g2(NN / 256, NJ / 128);
  k_gemm<<<g2, 512, 0, stream>>>(adjb, St, b1, adj, q, partial);
  // K3: reduce partials + final tiny GEMM
  k_out<<<1, 1024, 0, stream>>>(partial, W2, b2, out);
}

// Round 14
// 97.350 us; speedup vs baseline: 1.3448x; 1.0407x over previous
//
#include <hip/hip_runtime.h>
#include <hip/hip_bf16.h>
#include <stdint.h>

typedef __attribute__((ext_vector_type(4))) float f32x4;
typedef __attribute__((ext_vector_type(8))) short short8;

#define NN 4096      // nodes
#define FIN 128
#define FHID 64
#define BATCH 32
#define NJ 2048      // BATCH * FHID

// ---------- helpers ----------
__device__ __forceinline__ unsigned short f2bf(float f) {
  unsigned u = __builtin_bit_cast(unsigned, f);
  u = (u + 0x7FFFu + ((u >> 16) & 1u)) >> 16;   // RNE
  return (unsigned short)u;
}
__device__ __forceinline__ float bf2f(unsigned short h) {
  unsigned u = ((unsigned)h) << 16;
  return __builtin_bit_cast(float, u);
}
__device__ __forceinline__ void gload_lds16(const void* g, void* l) {
  __builtin_amdgcn_global_load_lds(
      (const __attribute__((address_space(1))) unsigned int*)g,
      (__attribute__((address_space(3))) unsigned int*)l, 16, 0, 0);
}

// ---------- K_pre: fused {adj fp32->bf16 convert} + {support^T GEMM} ----------
// Blocks [0,1024): support (MFMA, W1^T in LDS). Blocks [1024,3072): convert,
// each thread 8 float4 (ILP for BW). Both memory-bound; one launch.
__global__ __launch_bounds__(256) void k_pre(const float* __restrict__ adj,
                                             unsigned short* __restrict__ adjb,
                                             const float* __restrict__ x,
                                             const float* __restrict__ W1,
                                             unsigned short* __restrict__ St) {
  __shared__ unsigned short W1t[FHID * 136];              // [h][f], pad 136
  __shared__ __align__(16) unsigned short T[FHID * 128];  // [h][m_loc]
  const int tid = threadIdx.x;

  if (blockIdx.x >= 1024) {
    // ---- convert branch: 2048 blocks x 256 thr x 8 float4 ----
    long base = ((long)blockIdx.x - 1024) * 2048 + tid;
    const f32x4* in = (const f32x4*)adj;
    f32x4 v[8];
    #pragma unroll
    for (int it = 0; it < 8; ++it) v[it] = in[base + it * 256];
    #pragma unroll
    for (int it = 0; it < 8; ++it) {
      ushort4 o;
      o.x = f2bf(v[it].x); o.y = f2bf(v[it].y);
      o.z = f2bf(v[it].z); o.w = f2bf(v[it].w);
      *(ushort4*)(adjb + (base + it * 256) * 4) = o;
    }
    return;
  }

  // ---- support branch (1024 blocks): St[b*64+h][m] = sum_f x[b][m][f]*W1[f][h]
  for (int i = tid; i < FIN * FHID; i += 256) {
    int f = i >> 6, h = i & 63;
    W1t[h * 136 + f] = f2bf(W1[i]);
  }
  __syncthreads();

  const int bb = blockIdx.x >> 5;
  const int m0 = (blockIdx.x & 31) * 128;
  const int lane = tid & 63, wv = tid >> 6;
  const int fr = lane & 15, fq = lane >> 4;

  short8 bfr[4][4];
  #pragma unroll
  for (int ni = 0; ni < 4; ++ni)
    #pragma unroll
    for (int ks = 0; ks < 4; ++ks)
      bfr[ni][ks] = *(const short8*)&W1t[(ni * 16 + fr) * 136 + ks * 32 + fq * 8];

  const float* xr0 = x + ((size_t)bb * NN + m0 + wv * 32 + fr) * FIN;
  const float* xr1 = xr0 + (size_t)16 * FIN;

  f32x4 z = {0.f, 0.f, 0.f, 0.f};
  f32x4 acc[2][4];
  #pragma unroll
  for (int mf = 0; mf < 2; ++mf)
    #pragma unroll
    for (int ni = 0; ni < 4; ++ni) acc[mf][ni] = z;

  #pragma unroll
  for (int ks = 0; ks < 4; ++ks) {
    #pragma unroll
    for (int mf = 0; mf < 2; ++mf) {
      const float* src = (mf ? xr1 : xr0) + ks * 32 + fq * 8;
      f32x4 lo = *(const f32x4*)src;
      f32x4 hi = *(const f32x4*)(src + 4);
      short8 a;
      #pragma unroll
      for (int j = 0; j < 4; ++j) { a[j] = (short)f2bf(lo[j]); a[4 + j] = (short)f2bf(hi[j]); }
      #pragma unroll
      for (int ni = 0; ni < 4; ++ni)
        acc[mf][ni] = __builtin_amdgcn_mfma_f32_16x16x32_bf16(a, bfr[ni][ks], acc[mf][ni], 0, 0, 0);
    }
  }

  const int cr = (lane >> 4) * 4, cc = lane & 15;
  #pragma unroll
  for (int mf = 0; mf < 2; ++mf)
    #pragma unroll
    for (int ni = 0; ni < 4; ++ni) {
      ushort4 o;
      o.x = f2bf(acc[mf][ni][0]); o.y = f2bf(acc[mf][ni][1]);
      o.z = f2bf(acc[mf][ni][2]); o.w = f2bf(acc[mf][ni][3]);
      *(ushort4*)&T[(ni * 16 + cc) * 128 + wv * 32 + mf * 16 + cr] = o;
    }
  __syncthreads();
  for (int u = tid; u < FHID * 16; u += 256) {
    int row = u >> 4, ch = u & 15;
    *(short8*)(St + (size_t)(bb * FHID + row) * NN + m0 + ch * 8) =
        *(const short8*)&T[row * 128 + ch * 8];
  }
}

// ---------- K2: fused GEMM + bias + relu + row-weighted aggregation ----------
// K-loop: R5-derived geometry (BM=256 x BN=128, BK=64, 8 waves 4M x 2N,
// per-wave 64x64, dbuf LDS 96 KB, reg-dbuf bvA, XOR-swizzle via pre-swizzled
// global source) with phases MERGED 4 -> 2: each phase = {reads; stages;
// [VMW]; BAR; LGKM0; 16-MFMA cluster}. 2 barriers/tile instead of 4.
// FIFO guards: steady VMW(6) after PhB stages (9 outstanding -> drains
// t-1-PhB's 3 = tile t+1 complete before its buf is read); prologue VMW(6);
// tile 62 VMW(0). Stage regions dead-after-read as in R5.
// Epilogue: weight relu(acc+bias) by adj[q_b][row], reduce -> partial.
#define VMW(N)  asm volatile("s_waitcnt vmcnt(" #N ")" ::: "memory")
#define LGKM0   asm volatile("s_waitcnt lgkmcnt(0)" ::: "memory")
#define BAR     __builtin_amdgcn_s_barrier()

__global__ __launch_bounds__(512, 1) void k_gemm(const unsigned short* __restrict__ A,
                                                 const unsigned short* __restrict__ Bt,
                                                 const float* __restrict__ b1,
                                                 const float* __restrict__ adj,
                                                 const int* __restrict__ q_ids,
                                                 float* __restrict__ partial) {
  __shared__ __align__(16) unsigned short As[2 * 16384];  // A: 256x64 dbuf, 64 KB
  __shared__ __align__(16) unsigned short Bs[2 * 8192];   // B: 128x64 dbuf, 32 KB
  __shared__ float adjw[2][256];                          // 2 KB (epilogue)
  __shared__ float red[8][64];                            // 2 KB (epilogue)

  const int tid  = threadIdx.x;
  const int lane = tid & 63;
  const int wv   = tid >> 6;
  const int wm   = wv >> 1;          // 0..3 (M)
  const int wn   = wv & 1;           // 0..1 (N)
  const int bm   = blockIdx.x * 256;
  const int bn   = blockIdx.y * 128;
  const int fr   = lane & 15;
  const int fq   = lane >> 4;

  // fragment LDS ushort offsets (buffer-relative)
  int offA[2][2][2], offB[4][2];
  #pragma unroll
  for (int h = 0; h < 2; ++h)
    #pragma unroll
    for (int m2 = 0; m2 < 2; ++m2) {
      int row = wm * 32 + h * 128 + m2 * 16 + fr;
      #pragma unroll
      for (int ks = 0; ks < 2; ++ks)
        offA[h][m2][ks] = row * 64 + ((((ks << 6) + (fq << 4)) ^ ((row & 7) << 4)) >> 1);
    }
  #pragma unroll
  for (int ni = 0; ni < 4; ++ni) {
    int row = wn * 32 + (ni & 1) * 16 + (ni >> 1) * 64 + fr;
    #pragma unroll
    for (int ks = 0; ks < 2; ++ks)
      offB[ni][ks] = row * 64 + ((((ks << 6) + (fq << 4)) ^ ((row & 7) << 4)) >> 1);
  }

  // staging addresses (pre-swizzled global source, linear LDS dest)
  const int srow = tid >> 3;
  const int scol = ((((tid & 7) << 4) ^ ((srow & 7) << 4)) >> 1);
  const unsigned short* gA00 = A + (size_t)(bm +   0 + srow) * NN + scol;
  const unsigned short* gA01 = A + (size_t)(bm +  64 + srow) * NN + scol;
  const unsigned short* gA10 = A + (size_t)(bm + 128 + srow) * NN + scol;
  const unsigned short* gA11 = A + (size_t)(bm + 192 + srow) * NN + scol;
  const unsigned short* gB0  = Bt + (size_t)(bn +  0 + srow) * NN + scol;
  const unsigned short* gB1  = Bt + (size_t)(bn + 64 + srow) * NN + scol;
  const int ld = tid * 8;

  f32x4 z = {0.f, 0.f, 0.f, 0.f};
  f32x4 acc[4][4];
  #pragma unroll
  for (int i = 0; i < 4; ++i)
    #pragma unroll
    for (int j = 0; j < 4; ++j) acc[i][j] = z;

  short8 av0[2][2], av1[2][2], bvB[2][2], bvA0[2][2], bvA1[2][2];

#define RD_AVA(Ac)                                                             \
    _Pragma("unroll") for (int m2 = 0; m2 < 2; ++m2)                           \
    _Pragma("unroll") for (int ks = 0; ks < 2; ++ks)                           \
      av0[m2][ks] = *(const short8*)((Ac) + offA[0][m2][ks]);
#define RD_AVB(Ac)                                                             \
    _Pragma("unroll") for (int m2 = 0; m2 < 2; ++m2)                           \
    _Pragma("unroll") for (int ks = 0; ks < 2; ++ks)                           \
      av1[m2][ks] = *(const short8*)((Ac) + offA[1][m2][ks]);
#define RD_BV(DST, Bb, P)                                                      \
    _Pragma("unroll") for (int n2 = 0; n2 < 2; ++n2)                           \
    _Pragma("unroll") for (int ks = 0; ks < 2; ++ks)                           \
      DST[n2][ks] = *(const short8*)((Bb) + offB[2 * (P) + n2][ks]);
#define MFMA8(MP, AV, BV, NP)                                                  \
    __builtin_amdgcn_s_setprio(1);                                             \
    _Pragma("unroll") for (int m2 = 0; m2 < 2; ++m2)                           \
    _Pragma("unroll") for (int n2 = 0; n2 < 2; ++n2)                           \
    _Pragma("unroll") for (int ks = 0; ks < 2; ++ks)                           \
      acc[2 * (MP) + m2][2 * (NP) + n2] = __builtin_amdgcn_mfma_f32_16x16x32_bf16( \
          AV[m2][ks], BV[n2][ks], acc[2 * (MP) + m2][2 * (NP) + n2], 0, 0, 0); \
    __builtin_amdgcn_s_setprio(0);

// One K-tile, 2 merged phases:
// PhA: {read A-h0 + B-np1; stage A00,A01,B1 (t+2); BAR; LGKM0;
//       MFMA Q(0,0)+Q(0,1)}   [A-h0/B1 regions dead after these reads]
// PhB: {read A-h1; stage A10,A11,B0 (t+2); VMW; BAR; LGKM0;
//       read bvA(t+1); MFMA Q(1,1)+Q(1,0)}
// VMW(6) after PhB stages: outstanding = t-1PhB(3) + tPhA(3) + tPhB(3) = 9
// -> drains oldest 3 = tile t+1's second half; t+1 fully landed.
#define TILE(CUR, BVA_C, BVA_N, KQ, DOS, VMWOP) {                              \
    const unsigned short* Ac = As + (CUR) * 16384;                             \
    const unsigned short* Bc = Bs + (CUR) * 8192;                              \
    const unsigned short* Bn = Bs + (1 - (CUR)) * 8192;                        \
    /* PhA */                                                                  \
    RD_AVA(Ac)                                                                 \
    RD_BV(bvB, Bc, 1)                                                          \
    if (DOS) {                                                                 \
      gload_lds16(gA00 + (KQ), As + (CUR) * 16384 + 0 * 4096 + ld);            \
      gload_lds16(gA01 + (KQ), As + (CUR) * 16384 + 1 * 4096 + ld);            \
      gload_lds16(gB1  + (KQ), Bs + (CUR) * 8192 + 1 * 4096 + ld);             \
    }                                                                          \
    BAR; LGKM0;                                                                \
    MFMA8(0, av0, BVA_C, 0)                                                    \
    MFMA8(0, av0, bvB, 1)                                                      \
    /* PhB */                                                                  \
    RD_AVB(Ac)                                                                 \
    if (DOS) {                                                                 \
      gload_lds16(gA10 + (KQ), As + (CUR) * 16384 + 2 * 4096 + ld);            \
      gload_lds16(gA11 + (KQ), As + (CUR) * 16384 + 3 * 4096 + ld);            \
      gload_lds16(gB0  + (KQ), Bs + (CUR) * 8192 + 0 * 4096 + ld);             \
    }                                                                          \
    VMWOP;                                                                     \
    BAR; LGKM0;                                                                \
    RD_BV(BVA_N, Bn, 0)                                                        \
    MFMA8(1, av1, bvB, 1)                                                      \
    MFMA8(1, av1, BVA_C, 0)                                                    \
  }

  // ---- prologue: stage tile0 -> buf0, tile1 -> buf1 ----
  gload_lds16(gB0,       Bs + 0 * 4096 + ld);
  gload_lds16(gB1,       Bs + 1 * 4096 + ld);
  gload_lds16(gA00,      As + 0 * 4096 + ld);
  gload_lds16(gA01,      As + 1 * 4096 + ld);
  gload_lds16(gA10,      As + 2 * 4096 + ld);
  gload_lds16(gA11,      As + 3 * 4096 + ld);
  gload_lds16(gB0  + 64, Bs + 8192 + 0 * 4096 + ld);
  gload_lds16(gB1  + 64, Bs + 8192 + 1 * 4096 + ld);
  gload_lds16(gA00 + 64, As + 16384 + 0 * 4096 + ld);
  gload_lds16(gA01 + 64, As + 16384 + 1 * 4096 + ld);
  gload_lds16(gA10 + 64, As + 16384 + 2 * 4096 + ld);
  gload_lds16(gA11 + 64, As + 16384 + 3 * 4096 + ld);
  VMW(6);                 // own tile-0 loads drained
  BAR;                    // => all waves' tile-0 loads visible
  RD_BV(bvA0, Bs, 0)      // prime bvA for tile 0 (drained at tile0 PhA LGKM0)

  // ---- main loop: 31 macro-iters = tiles 0..61 ----
  int kq = 128;           // k-elem offset of tile t+2
  #pragma unroll 1
  for (int g = 0; g < 31; ++g) {
    TILE(0, bvA0, bvA1, kq,      1, VMW(6))
    TILE(1, bvA1, bvA0, kq + 64, 1, VMW(6))
    kq += 128;
  }
  // ---- tile 62 (buf0): no staging; drain everything for tile 63 ----
  TILE(0, bvA0, bvA1, 0, 0, VMW(0))
  // ---- tile 63 (buf1): last, no staging / no vmcnt / no bvA-next ----
  {
    const unsigned short* Ac = As + 16384;
    const unsigned short* Bc = Bs + 8192;
    RD_AVA(Ac)
    RD_BV(bvB, Bc, 1)
    BAR; LGKM0;
    MFMA8(0, av0, bvA1, 0)
    MFMA8(0, av0, bvB, 1)
    RD_AVB(Ac)
    BAR; LGKM0;
    MFMA8(1, av1, bvB, 1)
    MFMA8(1, av1, bvA1, 0)
  }
#undef RD_AVA
#undef RD_AVB
#undef RD_BV
#undef MFMA8
#undef TILE

  // ---- fused epilogue: bias + relu + weight by adj[q_b][row] + reduce ----
  const int b0 = bn >> 6;
  {
    int bsel = tid >> 8;           // 0 or 1
    int rloc = tid & 255;
    adjw[bsel][rloc] = adj[(size_t)q_ids[b0 + bsel] * NN + bm + rloc];
  }
  __syncthreads();

  const int cr = (lane >> 4) * 4;
  const int cc = lane & 15;
  float ps[4];
  #pragma unroll
  for (int ni = 0; ni < 4; ++ni) {
    int colh = wn * 32 + (ni & 1) * 16 + cc;   // h index (col & 63)
    float bias = b1[colh];
    float s = 0.f;
    #pragma unroll
    for (int mi = 0; mi < 4; ++mi) {
      int rowl = wm * 32 + (mi & 1) * 16 + (mi >> 1) * 128 + cr;
      #pragma unroll
      for (int r = 0; r < 4; ++r) {
        float v = acc[mi][ni][r] + bias;
        v = v > 0.f ? v : 0.f;
        s += adjw[ni >> 1][rowl + r] * v;
      }
    }
    ps[ni] = s;
  }
  // reduce across fq groups (lanes differing in bits 4,5)
  #pragma unroll
  for (int ni = 0; ni < 4; ++ni) {
    ps[ni] += __shfl_xor(ps[ni], 16, 64);
    ps[ni] += __shfl_xor(ps[ni], 32, 64);
  }
  if (lane < 16) {
    #pragma unroll
    for (int ni = 0; ni < 4; ++ni)
      red[wm * 2 + wn][ni * 16 + cc] = ps[ni];
  }
  __syncthreads();
  if (tid < 128) {
    int colLocal = tid;
    int wn2 = (colLocal >> 5) & 1;
    int ni2 = ((colLocal >> 6) << 1) | ((colLocal >> 4) & 1);
    int cc2 = colLocal & 15;
    float s = red[0 + wn2][ni2 * 16 + cc2] + red[2 + wn2][ni2 * 16 + cc2]
            + red[4 + wn2][ni2 * 16 + cc2] + red[6 + wn2][ni2 * 16 + cc2];
    partial[(size_t)blockIdx.x * NJ + bn + colLocal] = s;
  }
}

// ---------- K4: out[b][l] = sum_h (sum_rb partial[rb][b*64+h]) * W2[h][l] + b2[l] ----------
__global__ __launch_bounds__(1024) void k_out(const float* __restrict__ partial,
                                              const float* __restrict__ W2,
                                              const float* __restrict__ b2,
                                              float* __restrict__ out) {
  __shared__ float aggs[BATCH * FHID];   // 2048
  int t = threadIdx.x;
  for (int idx = t; idx < BATCH * FHID; idx += 1024) {
    float s = 0.f;
    #pragma unroll
    for (int c = 0; c < 16; ++c) s += partial[c * NJ + idx];
    aggs[idx] = s;
  }
  __syncthreads();
  int b = t >> 5, l = t & 31;
  float o = b2[l];
  #pragma unroll
  for (int h = 0; h < FHID; ++h) o += aggs[b * FHID + h] * W2[h * 32 + l];
  out[b * 32 + l] = o;
}

extern "C" void kernel_launch(void* const* d_in, const int* in_sizes, int n_in,
                              void* d_out, int out_size, void* d_ws, size_t ws_size,
                              hipStream_t stream) {
  const float* x   = (const float*)d_in[0];
  const int*   q   = (const int*)d_in[1];
  const float* adj = (const float*)d_in[2];
  const float* W1  = (const float*)d_in[3];
  const float* b1  = (const float*)d_in[4];
  const float* W2  = (const float*)d_in[5];
  const float* b2  = (const float*)d_in[6];
  float* out = (float*)d_out;

  char* ws = (char*)d_ws;
  unsigned short* adjb   = (unsigned short*)ws;                              // 32 MB
  unsigned short* St     = (unsigned short*)(ws + (size_t)32 * 1024 * 1024); // 16 MB
  float*          partial= (float*)(ws + (size_t)48 * 1024 * 1024);          // 128 KB

  // K_pre: fused convert + support (3072 blocks: 1024 support + 2048 convert)
  k_pre<<<3072, 256, 0, stream>>>(adj, adjb, x, W1, St);
  // K2: fused GEMM + bias/relu + row-weighted aggregation (2-barrier tiles)
  dim3 g2(NN / 256, NJ / 128);
  k_gemm<<<g2, 512, 0, stream>>>(adjb, St, b1, adj, q, partial);
  // K3: reduce partials + final tiny GEMM
  k_out<<<1, 1024, 0, stream>>>(partial, W2, b2, out);
}

// Round 16
// 94.759 us; speedup vs baseline: 1.3816x; 1.0273x over previous
//
#include <hip/hip_runtime.h>
#include <hip/hip_bf16.h>
#include <stdint.h>

typedef __attribute__((ext_vector_type(4))) float f32x4;
typedef __attribute__((ext_vector_type(8))) short short8;

#define NN 4096      // nodes
#define FIN 128
#define FHID 64
#define BATCH 32
#define NJ 2048      // BATCH * FHID

// ---------- helpers ----------
__device__ __forceinline__ unsigned short f2bf(float f) {
  unsigned u = __builtin_bit_cast(unsigned, f);
  u = (u + 0x7FFFu + ((u >> 16) & 1u)) >> 16;   // RNE
  return (unsigned short)u;
}
__device__ __forceinline__ float bf2f(unsigned short h) {
  unsigned u = ((unsigned)h) << 16;
  return __builtin_bit_cast(float, u);
}
__device__ __forceinline__ void gload_lds16(const void* g, void* l) {
  __builtin_amdgcn_global_load_lds(
      (const __attribute__((address_space(1))) unsigned int*)g,
      (__attribute__((address_space(3))) unsigned int*)l, 16, 0, 0);
}

// ---------- K_pre: fused {adj fp32->bf16 convert} + {support^T GEMM} ----------
__global__ __launch_bounds__(256) void k_pre(const float* __restrict__ adj,
                                             unsigned short* __restrict__ adjb,
                                             const float* __restrict__ x,
                                             const float* __restrict__ W1,
                                             unsigned short* __restrict__ St) {
  __shared__ unsigned short W1t[FHID * 136];              // [h][f], pad 136
  __shared__ __align__(16) unsigned short T[FHID * 128];  // [h][m_loc]
  const int tid = threadIdx.x;

  if (blockIdx.x >= 1024) {
    // ---- convert branch: 2048 blocks x 256 thr x 8 float4 ----
    long base = ((long)blockIdx.x - 1024) * 2048 + tid;
    const f32x4* in = (const f32x4*)adj;
    f32x4 v[8];
    #pragma unroll
    for (int it = 0; it < 8; ++it) v[it] = in[base + it * 256];
    #pragma unroll
    for (int it = 0; it < 8; ++it) {
      ushort4 o;
      o.x = f2bf(v[it].x); o.y = f2bf(v[it].y);
      o.z = f2bf(v[it].z); o.w = f2bf(v[it].w);
      *(ushort4*)(adjb + (base + it * 256) * 4) = o;
    }
    return;
  }

  // ---- support branch (1024 blocks) ----
  for (int i = tid; i < FIN * FHID; i += 256) {
    int f = i >> 6, h = i & 63;
    W1t[h * 136 + f] = f2bf(W1[i]);
  }
  __syncthreads();

  const int bb = blockIdx.x >> 5;
  const int m0 = (blockIdx.x & 31) * 128;
  const int lane = tid & 63, wv = tid >> 6;
  const int fr = lane & 15, fq = lane >> 4;

  short8 bfr[4][4];
  #pragma unroll
  for (int ni = 0; ni < 4; ++ni)
    #pragma unroll
    for (int ks = 0; ks < 4; ++ks)
      bfr[ni][ks] = *(const short8*)&W1t[(ni * 16 + fr) * 136 + ks * 32 + fq * 8];

  const float* xr0 = x + ((size_t)bb * NN + m0 + wv * 32 + fr) * FIN;
  const float* xr1 = xr0 + (size_t)16 * FIN;

  f32x4 z = {0.f, 0.f, 0.f, 0.f};
  f32x4 acc[2][4];
  #pragma unroll
  for (int mf = 0; mf < 2; ++mf)
    #pragma unroll
    for (int ni = 0; ni < 4; ++ni) acc[mf][ni] = z;

  #pragma unroll
  for (int ks = 0; ks < 4; ++ks) {
    #pragma unroll
    for (int mf = 0; mf < 2; ++mf) {
      const float* src = (mf ? xr1 : xr0) + ks * 32 + fq * 8;
      f32x4 lo = *(const f32x4*)src;
      f32x4 hi = *(const f32x4*)(src + 4);
      short8 a;
      #pragma unroll
      for (int j = 0; j < 4; ++j) { a[j] = (short)f2bf(lo[j]); a[4 + j] = (short)f2bf(hi[j]); }
      #pragma unroll
      for (int ni = 0; ni < 4; ++ni)
        acc[mf][ni] = __builtin_amdgcn_mfma_f32_16x16x32_bf16(a, bfr[ni][ks], acc[mf][ni], 0, 0, 0);
    }
  }

  const int cr = (lane >> 4) * 4, cc = lane & 15;
  #pragma unroll
  for (int mf = 0; mf < 2; ++mf)
    #pragma unroll
    for (int ni = 0; ni < 4; ++ni) {
      ushort4 o;
      o.x = f2bf(acc[mf][ni][0]); o.y = f2bf(acc[mf][ni][1]);
      o.z = f2bf(acc[mf][ni][2]); o.w = f2bf(acc[mf][ni][3]);
      *(ushort4*)&T[(ni * 16 + cc) * 128 + wv * 32 + mf * 16 + cr] = o;
    }
  __syncthreads();
  for (int u = tid; u < FHID * 16; u += 256) {
    int row = u >> 4, ch = u & 15;
    *(short8*)(St + (size_t)(bb * FHID + row) * NN + m0 + ch * 8) =
        *(const short8*)&T[row * 128 + ch * 8];
  }
}

// ---------- K2: fused GEMM + bias + relu + row-weighted aggregation ----------
// Geometry: BM=256 x BN=128, BK=64, 8 waves 4M x 2N, per-wave 64x64,
// dbuf LDS 96 KB, XOR-swizzle via pre-swizzled global source.
// Schedule: 2 phases/K-tile with RACE-SAFE staging: every staged region is
// written one full barrier interval AFTER its last ds_read (R12's proven
// separation), at R13's barrier count.
//   PhA(t): read A-h0,B0,B1; VMW(6); stage second(t+1)={A10,A11}->other buf
//           (read at t-1-PhB, barrier since); BAR; LGKM0; MFMA Q(0,0)+Q(0,1).
//   PhB(t): read A-h1; VMW(6); stage first(t+2)={A00,A01,B0,B1}->cur buf
//           (read at t-PhA, barrier since); BAR; LGKM0; MFMA Q(1,1)+Q(1,0).
// FIFO (VMW before stages): steady outstanding 10/8 -> VMW(6) drains exactly
// the batch this phase reads. Prologue: t0(6)+first(t1)(4), VMW(4).
// Tail: t62 {VMW6,VMW6,DOSB=0}; t63 {VMW2,VMW0}.
#define VMW(N)  asm volatile("s_waitcnt vmcnt(" #N ")" ::: "memory")
#define LGKM0   asm volatile("s_waitcnt lgkmcnt(0)" ::: "memory")
#define BAR     __builtin_amdgcn_s_barrier()

__global__ __launch_bounds__(512, 1) void k_gemm(const unsigned short* __restrict__ A,
                                                 const unsigned short* __restrict__ Bt,
                                                 const float* __restrict__ b1,
                                                 const float* __restrict__ adj,
                                                 const int* __restrict__ q_ids,
                                                 float* __restrict__ partial) {
  __shared__ __align__(16) unsigned short As[2 * 16384];  // A: 256x64 dbuf, 64 KB
  __shared__ __align__(16) unsigned short Bs[2 * 8192];   // B: 128x64 dbuf, 32 KB
  __shared__ float adjw[2][256];                          // 2 KB (epilogue)
  __shared__ float red[8][64];                            // 2 KB (epilogue)

  const int tid  = threadIdx.x;
  const int lane = tid & 63;
  const int wv   = tid >> 6;
  const int wm   = wv >> 1;          // 0..3 (M)
  const int wn   = wv & 1;           // 0..1 (N)
  const int bm   = blockIdx.x * 256;
  const int bn   = blockIdx.y * 128;
  const int fr   = lane & 15;
  const int fq   = lane >> 4;

  // fragment LDS ushort offsets (buffer-relative)
  int offA[2][2][2], offB[4][2];
  #pragma unroll
  for (int h = 0; h < 2; ++h)
    #pragma unroll
    for (int m2 = 0; m2 < 2; ++m2) {
      int row = wm * 32 + h * 128 + m2 * 16 + fr;
      #pragma unroll
      for (int ks = 0; ks < 2; ++ks)
        offA[h][m2][ks] = row * 64 + ((((ks << 6) + (fq << 4)) ^ ((row & 7) << 4)) >> 1);
    }
  #pragma unroll
  for (int ni = 0; ni < 4; ++ni) {
    int row = wn * 32 + (ni & 1) * 16 + (ni >> 1) * 64 + fr;
    #pragma unroll
    for (int ks = 0; ks < 2; ++ks)
      offB[ni][ks] = row * 64 + ((((ks << 6) + (fq << 4)) ^ ((row & 7) << 4)) >> 1);
  }

  // staging addresses (pre-swizzled global source, linear LDS dest)
  const int srow = tid >> 3;
  const int scol = ((((tid & 7) << 4) ^ ((srow & 7) << 4)) >> 1);
  const unsigned short* gA00 = A + (size_t)(bm +   0 + srow) * NN + scol;
  const unsigned short* gA01 = A + (size_t)(bm +  64 + srow) * NN + scol;
  const unsigned short* gA10 = A + (size_t)(bm + 128 + srow) * NN + scol;
  const unsigned short* gA11 = A + (size_t)(bm + 192 + srow) * NN + scol;
  const unsigned short* gB0  = Bt + (size_t)(bn +  0 + srow) * NN + scol;
  const unsigned short* gB1  = Bt + (size_t)(bn + 64 + srow) * NN + scol;
  const int ld = tid * 8;

  f32x4 z = {0.f, 0.f, 0.f, 0.f};
  f32x4 acc[4][4];
  #pragma unroll
  for (int i = 0; i < 4; ++i)
    #pragma unroll
    for (int j = 0; j < 4; ++j) acc[i][j] = z;

  short8 av0[2][2], av1[2][2], bv0[2][2], bv1[2][2];

#define RD_AVA(Ac)                                                             \
    _Pragma("unroll") for (int m2 = 0; m2 < 2; ++m2)                           \
    _Pragma("unroll") for (int ks = 0; ks < 2; ++ks)                           \
      av0[m2][ks] = *(const short8*)((Ac) + offA[0][m2][ks]);
#define RD_AVB(Ac)                                                             \
    _Pragma("unroll") for (int m2 = 0; m2 < 2; ++m2)                           \
    _Pragma("unroll") for (int ks = 0; ks < 2; ++ks)                           \
      av1[m2][ks] = *(const short8*)((Ac) + offA[1][m2][ks]);
#define RD_BV(DST, Bb, P)                                                      \
    _Pragma("unroll") for (int n2 = 0; n2 < 2; ++n2)                           \
    _Pragma("unroll") for (int ks = 0; ks < 2; ++ks)                           \
      DST[n2][ks] = *(const short8*)((Bb) + offB[2 * (P) + n2][ks]);
#define MFMA8(MP, AV, BV, NP)                                                  \
    __builtin_amdgcn_s_setprio(1);                                             \
    _Pragma("unroll") for (int m2 = 0; m2 < 2; ++m2)                           \
    _Pragma("unroll") for (int n2 = 0; n2 < 2; ++n2)                           \
    _Pragma("unroll") for (int ks = 0; ks < 2; ++ks)                           \
      acc[2 * (MP) + m2][2 * (NP) + n2] = __builtin_amdgcn_mfma_f32_16x16x32_bf16( \
          AV[m2][ks], BV[n2][ks], acc[2 * (MP) + m2][2 * (NP) + n2], 0, 0, 0); \
    __builtin_amdgcn_s_setprio(0);

// Race-safe 2-phase tile. KOA = k-offset of second-batch(t+1);
// KOB = k-offset of first-batch(t+2).
#define TILE(CUR, KOA, KOB, DOSA, DOSB, VMWA, VMWB) {                          \
    const unsigned short* Ac = As + (CUR) * 16384;                             \
    const unsigned short* Bc = Bs + (CUR) * 8192;                              \
    /* PhA */                                                                  \
    RD_AVA(Ac)                                                                 \
    RD_BV(bv0, Bc, 0)                                                          \
    RD_BV(bv1, Bc, 1)                                                          \
    VMWA;                                                                      \
    if (DOSA) {  /* second(t+1) -> other buf: regions read at t-1-PhB */       \
      gload_lds16(gA10 + (KOA), As + (1 - (CUR)) * 16384 + 2 * 4096 + ld);     \
      gload_lds16(gA11 + (KOA), As + (1 - (CUR)) * 16384 + 3 * 4096 + ld);     \
    }                                                                          \
    BAR; LGKM0;                                                                \
    MFMA8(0, av0, bv0, 0)                                                      \
    MFMA8(0, av0, bv1, 1)                                                      \
    /* PhB */                                                                  \
    RD_AVB(Ac)                                                                 \
    VMWB;                                                                      \
    if (DOSB) {  /* first(t+2) -> cur buf: regions read at this tile's PhA */  \
      gload_lds16(gA00 + (KOB), As + (CUR) * 16384 + 0 * 4096 + ld);           \
      gload_lds16(gA01 + (KOB), As + (CUR) * 16384 + 1 * 4096 + ld);           \
      gload_lds16(gB0  + (KOB), Bs + (CUR) * 8192 + 0 * 4096 + ld);            \
      gload_lds16(gB1  + (KOB), Bs + (CUR) * 8192 + 1 * 4096 + ld);            \
    }                                                                          \
    BAR; LGKM0;                                                                \
    MFMA8(1, av1, bv1, 1)                                                      \
    MFMA8(1, av1, bv0, 0)                                                      \
  }

  // ---- prologue: t0 full -> buf0 (6), first(t1) -> buf1 (4) ----
  gload_lds16(gA00,      As + 0 * 4096 + ld);
  gload_lds16(gA01,      As + 1 * 4096 + ld);
  gload_lds16(gB0,       Bs + 0 * 4096 + ld);
  gload_lds16(gB1,       Bs + 1 * 4096 + ld);
  gload_lds16(gA10,      As + 2 * 4096 + ld);
  gload_lds16(gA11,      As + 3 * 4096 + ld);
  gload_lds16(gA00 + 64, As + 16384 + 0 * 4096 + ld);
  gload_lds16(gA01 + 64, As + 16384 + 1 * 4096 + ld);
  gload_lds16(gB0  + 64, Bs + 8192 + 0 * 4096 + ld);
  gload_lds16(gB1  + 64, Bs + 8192 + 1 * 4096 + ld);
  VMW(4);                 // t0's 6 loads drained; first(t1) in flight
  BAR;                    // => all waves' t0 data visible

  // ---- main loop: 31 macro-iters = tiles 0..61 ----
  int koa = 64;           // k-offset of second(t+1) at even tile
  int kob = 128;          // k-offset of first(t+2) at even tile
  #pragma unroll 1
  for (int g = 0; g < 31; ++g) {
    TILE(0, koa,      kob,      1, 1, VMW(6), VMW(6))
    TILE(1, koa + 64, kob + 64, 1, 1, VMW(6), VMW(6))
    koa += 128; kob += 128;
  }
  // ---- tile 62 (buf0): stage second(63) only ----
  TILE(0, 63 * 64, 0, 1, 0, VMW(6), VMW(6))
  // ---- tile 63 (buf1): last, no staging ----
  TILE(1, 0, 0, 0, 0, VMW(2), VMW(0))
#undef RD_AVA
#undef RD_AVB
#undef RD_BV
#undef MFMA8
#undef TILE

  // ---- fused epilogue: bias + relu + weight by adj[q_b][row] + reduce ----
  const int b0 = bn >> 6;
  {
    int bsel = tid >> 8;           // 0 or 1
    int rloc = tid & 255;
    adjw[bsel][rloc] = adj[(size_t)q_ids[b0 + bsel] * NN + bm + rloc];
  }
  __syncthreads();

  const int cr = (lane >> 4) * 4;
  const int cc = lane & 15;
  float ps[4];
  #pragma unroll
  for (int ni = 0; ni < 4; ++ni) {
    int colh = wn * 32 + (ni & 1) * 16 + cc;   // h index (col & 63)
    float bias = b1[colh];
    float s = 0.f;
    #pragma unroll
    for (int mi = 0; mi < 4; ++mi) {
      int rowl = wm * 32 + (mi & 1) * 16 + (mi >> 1) * 128 + cr;
      #pragma unroll
      for (int r = 0; r < 4; ++r) {
        float v = acc[mi][ni][r] + bias;
        v = v > 0.f ? v : 0.f;
        s += adjw[ni >> 1][rowl + r] * v;
      }
    }
    ps[ni] = s;
  }
  // reduce across fq groups (lanes differing in bits 4,5)
  #pragma unroll
  for (int ni = 0; ni < 4; ++ni) {
    ps[ni] += __shfl_xor(ps[ni], 16, 64);
    ps[ni] += __shfl_xor(ps[ni], 32, 64);
  }
  if (lane < 16) {
    #pragma unroll
    for (int ni = 0; ni < 4; ++ni)
      red[wm * 2 + wn][ni * 16 + cc] = ps[ni];
  }
  __syncthreads();
  if (tid < 128) {
    int colLocal = tid;
    int wn2 = (colLocal >> 5) & 1;
    int ni2 = ((colLocal >> 6) << 1) | ((colLocal >> 4) & 1);
    int cc2 = colLocal & 15;
    float s = red[0 + wn2][ni2 * 16 + cc2] + red[2 + wn2][ni2 * 16 + cc2]
            + red[4 + wn2][ni2 * 16 + cc2] + red[6 + wn2][ni2 * 16 + cc2];
    partial[(size_t)blockIdx.x * NJ + bn + colLocal] = s;
  }
}

// ---------- K4: out[b][l] = sum_h (sum_rb partial[rb][b*64+h]) * W2[h][l] + b2[l] ----------
__global__ __launch_bounds__(1024) void k_out(const float* __restrict__ partial,
                                              const float* __restrict__ W2,
                                              const float* __restrict__ b2,
                                              float* __restrict__ out) {
  __shared__ float aggs[BATCH * FHID];   // 2048
  int t = threadIdx.x;
  for (int idx = t; idx < BATCH * FHID; idx += 1024) {
    float s = 0.f;
    #pragma unroll
    for (int c = 0; c < 16; ++c) s += partial[c * NJ + idx];
    aggs[idx] = s;
  }
  __syncthreads();
  int b = t >> 5, l = t & 31;
  float o = b2[l];
  #pragma unroll
  for (int h = 0; h < FHID; ++h) o += aggs[b * FHID + h] * W2[h * 32 + l];
  out[b * 32 + l] = o;
}

extern "C" void kernel_launch(void* const* d_in, const int* in_sizes, int n_in,
                              void* d_out, int out_size, void* d_ws, size_t ws_size,
                              hipStream_t stream) {
  const float* x   = (const float*)d_in[0];
  const int*   q   = (const int*)d_in[1];
  const float* adj = (const float*)d_in[2];
  const float* W1  = (const float*)d_in[3];
  const float* b1  = (const float*)d_in[4];
  const float* W2  = (const float*)d_in[5];
  const float* b2  = (const float*)d_in[6];
  float* out = (float*)d_out;

  char* ws = (char*)d_ws;
  unsigned short* adjb   = (unsigned short*)ws;                              // 32 MB
  unsigned short* St     = (unsigned short*)(ws + (size_t)32 * 1024 * 1024); // 16 MB
  float*          partial= (float*)(ws + (size_t)48 * 1024 * 1024);          // 128 KB

  // K_pre: fused convert + support (3072 blocks: 1024 support + 2048 convert)
  k_pre<<<3072, 256, 0, stream>>>(adj, adjb, x, W1, St);
  // K2: fused GEMM + bias/relu + aggregation (race-safe 2-phase tiles)
  dim3 g2(NN / 256, NJ / 128);
  k_gemm<<<g2, 512, 0, stream>>>(adjb, St, b1, adj, q, partial);
  // K3: reduce partials + final tiny GEMM
  k_out<<<1, 1024, 0, stream>>>(partial, W2, b2, out);
}